// Round 1
// baseline (116.583 us; speedup 1.0000x reference)
//
#include <hip/hip_runtime.h>

// out[b,n,f] = lo[f]*x[b,n,f-1] + hi[f]*x[b,n,f+1]
// lo[f] = adj_t[f, f-1] for f>=1 else 0
// hi[f] = adj_t[f, f+1] for f<=T-2 else 0
//
// B=64, N=512, T=512. Pure memory-bound band stencil:
// ~64 MiB read + ~64 MiB write -> roofline ~22 us @ 6.3 TB/s.

#define T_DIM 512

// Extract the two off-diagonals of adj_t into ws: ws[0..T) = lo, ws[T..2T) = hi
__global__ void coef_prep(const float* __restrict__ adj, float* __restrict__ ws) {
    int f = blockIdx.x * blockDim.x + threadIdx.x;
    if (f < T_DIM) {
        ws[f]         = (f >= 1)        ? adj[(size_t)f * T_DIM + (f - 1)] : 0.0f;
        ws[T_DIM + f] = (f < T_DIM - 1) ? adj[(size_t)f * T_DIM + (f + 1)] : 0.0f;
    }
}

// One thread computes 4 contiguous outputs via float4. Neighbor elements
// x[f-1] / x[f+4] are scalar loads that hit L1 (same or adjacent lines).
// Rows are contiguous (T=512), so f4 = vec_index & 127.
__global__ __launch_bounds__(256) void band_stencil(
        const float* __restrict__ x,
        const float* __restrict__ ws,
        float* __restrict__ out,
        long total_vec /* B*N*T/4 */) {
    long v = (long)blockIdx.x * blockDim.x + threadIdx.x;
    if (v >= total_vec) return;

    const int nvec_per_row = T_DIM / 4;              // 128 (power of 2)
    int f4 = (int)(v & (nvec_per_row - 1));          // vec index within row

    const float4* __restrict__ x4 = (const float4*)x;
    float4 xv = x4[v];

    long g = v * 4;                                  // element index of x[f]
    // Cross-row reads at row boundaries are multiplied by a 0 coefficient,
    // so only the ends of the whole array need guarding.
    float xm1 = (g > 0)                  ? x[g - 1] : 0.0f;
    float xp4 = (g + 4 < total_vec * 4)  ? x[g + 4] : 0.0f;

    const float4* __restrict__ lo4 = (const float4*)ws;
    const float4* __restrict__ hi4 = (const float4*)(ws + T_DIM);
    float4 lo = lo4[f4];
    float4 hi = hi4[f4];

    float4 o;
    o.x = lo.x * xm1  + hi.x * xv.y;
    o.y = lo.y * xv.x + hi.y * xv.z;
    o.z = lo.z * xv.y + hi.z * xv.w;
    o.w = lo.w * xv.z + hi.w * xp4;

    ((float4*)out)[v] = o;
}

extern "C" void kernel_launch(void* const* d_in, const int* in_sizes, int n_in,
                              void* d_out, int out_size, void* d_ws, size_t ws_size,
                              hipStream_t stream) {
    const float* x   = (const float*)d_in[0];   // [B, N, T] fp32
    const float* adj = (const float*)d_in[1];   // [T, T] fp32
    float* out = (float*)d_out;                 // [B, N, T] fp32
    float* ws  = (float*)d_ws;                  // >= 2*T floats

    // 1) extract band coefficients (d_ws is re-poisoned every call, so always run)
    coef_prep<<<(T_DIM + 255) / 256, 256, 0, stream>>>(adj, ws);

    // 2) streaming band stencil
    long total_vec = (long)out_size / 4;        // 64*512*512/4 = 4,194,304
    long nblocks = (total_vec + 255) / 256;     // 16384
    band_stencil<<<(int)nblocks, 256, 0, stream>>>(x, ws, out, total_vec);
}